// Round 1
// baseline (1938.920 us; speedup 1.0000x reference)
//
#include <hip/hip_runtime.h>

#define BB 512
#define TT 1024
#define DD 64
#define HH 32
#define CC 4
#define IN0 68          // D + L*C
#define G4 128          // 4*H

__device__ __forceinline__ float rcpf(float x) { return __builtin_amdgcn_rcpf(x); }
__device__ __forceinline__ float sigm(float x) { return rcpf(1.0f + __expf(-x)); }
__device__ __forceinline__ float tanh_f(float x) {
    // tanh(x) = 1 - 2/(exp(2x)+1); saturates correctly for |x| large
    return 1.0f - 2.0f * rcpf(__expf(2.0f * x) + 1.0f);
}

extern "C" __global__ void __launch_bounds__(128)
lstm_opt_enc(const float* __restrict__ states,   // [B,T,D]
             const float* __restrict__ taup,     // [1]
             const float* __restrict__ gumbel,   // [T,B,1,C]
             const float* __restrict__ w_ih0,    // [128,68]
             const float* __restrict__ w_hh0,    // [128,32]
             const float* __restrict__ b_ih0,    // [128]
             const float* __restrict__ b_hh0,    // [128]
             const float* __restrict__ w_ih1,    // [128,32]
             const float* __restrict__ w_hh1,    // [128,32]
             const float* __restrict__ b_ih1,    // [128]
             const float* __restrict__ b_hh1,    // [128]
             const float* __restrict__ w_lin,    // [4,32]
             const float* __restrict__ b_lin,    // [4]
             float* __restrict__ out)            // [B,T,4]
{
    const int b = blockIdx.x;
    const int j = threadIdx.x;   // gate index 0..127

    __shared__ __align__(16) float xbuf[IN0];    // [0..63]=states_t, [64..67]=ct
    __shared__ __align__(16) float h1buf[HH];
    __shared__ __align__(16) float h2buf[HH];
    __shared__ __align__(16) float zbuf[G4];
    __shared__ __align__(16) float qbuf[CC];
    __shared__ __align__(16) float wlin_s[CC * HH];
    __shared__ float blin_s[CC];

    // ---- load weights into registers (thread j owns gate row j) ----
    float wi0[IN0], wh0[HH], wi1[HH], wh1[HH];
#pragma unroll
    for (int k = 0; k < IN0; ++k) wi0[k] = w_ih0[j * IN0 + k];
#pragma unroll
    for (int k = 0; k < HH; ++k)  wh0[k] = w_hh0[j * HH + k];
#pragma unroll
    for (int k = 0; k < HH; ++k)  wi1[k] = w_ih1[j * HH + k];
#pragma unroll
    for (int k = 0; k < HH; ++k)  wh1[k] = w_hh1[j * HH + k];
    const float bias0 = b_ih0[j] + b_hh0[j];
    const float bias1 = b_ih1[j] + b_hh1[j];
    const float inv_tau = rcpf(taup[0]);

    wlin_s[j] = w_lin[j];                 // exactly 128 elements
    if (j < CC) blin_s[j] = b_lin[j];
    if (j < HH) { h1buf[j] = 0.0f; h2buf[j] = 0.0f; }
    if (j >= DD && j < IN0) xbuf[j] = (j == DD) ? 1.0f : 0.0f;  // ct = one-hot(0)

    float c1 = 0.0f, c2 = 0.0f;           // cell state for unit j (lanes j<32)

    const float* __restrict__ sb = states + (size_t)b * TT * DD;
    float* __restrict__ ob = out + (size_t)b * TT * CC;

    for (int t = 0; t < TT; ++t) {
        // stage x_t (coalesced 256B per block)
        if (j < DD) xbuf[j] = sb[t * DD + j];
        __syncthreads();                                   // A: xbuf(+ct) ready

        // ---- layer 0 gate j: dot-68 over x + dot-32 over h1 ----
        float a0 = 0.f, a1 = 0.f, a2 = 0.f, a3 = 0.f;
#pragma unroll
        for (int k4 = 0; k4 < IN0 / 4; ++k4) {
            float4 xv = ((const float4*)xbuf)[k4];
            a0 = fmaf(wi0[4 * k4 + 0], xv.x, a0);
            a1 = fmaf(wi0[4 * k4 + 1], xv.y, a1);
            a2 = fmaf(wi0[4 * k4 + 2], xv.z, a2);
            a3 = fmaf(wi0[4 * k4 + 3], xv.w, a3);
        }
#pragma unroll
        for (int k4 = 0; k4 < HH / 4; ++k4) {
            float4 hv = ((const float4*)h1buf)[k4];
            a0 = fmaf(wh0[4 * k4 + 0], hv.x, a0);
            a1 = fmaf(wh0[4 * k4 + 1], hv.y, a1);
            a2 = fmaf(wh0[4 * k4 + 2], hv.z, a2);
            a3 = fmaf(wh0[4 * k4 + 3], hv.w, a3);
        }
        zbuf[j] = bias0 + ((a0 + a1) + (a2 + a3));
        __syncthreads();                                   // B: z0 ready

        if (j < HH) {
            float zi = zbuf[j], zf = zbuf[j + 32], zg = zbuf[j + 64], zo = zbuf[j + 96];
            c1 = sigm(zf) * c1 + sigm(zi) * tanh_f(zg);
            h1buf[j] = sigm(zo) * tanh_f(c1);
        }
        __syncthreads();                                   // C: h1 ready

        // ---- layer 1 gate j: dot-32 over h1 + dot-32 over h2 ----
        a0 = a1 = a2 = a3 = 0.f;
#pragma unroll
        for (int k4 = 0; k4 < HH / 4; ++k4) {
            float4 hv = ((const float4*)h1buf)[k4];
            float4 gv = ((const float4*)h2buf)[k4];
            a0 = fmaf(wi1[4 * k4 + 0], hv.x, a0);
            a1 = fmaf(wi1[4 * k4 + 1], hv.y, a1);
            a2 = fmaf(wi1[4 * k4 + 2], hv.z, a2);
            a3 = fmaf(wi1[4 * k4 + 3], hv.w, a3);
            a0 = fmaf(wh1[4 * k4 + 0], gv.x, a0);
            a1 = fmaf(wh1[4 * k4 + 1], gv.y, a1);
            a2 = fmaf(wh1[4 * k4 + 2], gv.z, a2);
            a3 = fmaf(wh1[4 * k4 + 3], gv.w, a3);
        }
        zbuf[j] = bias1 + ((a0 + a1) + (a2 + a3));
        __syncthreads();                                   // D: z1 ready

        if (j < HH) {
            float zi = zbuf[j], zf = zbuf[j + 32], zg = zbuf[j + 64], zo = zbuf[j + 96];
            c2 = sigm(zf) * c2 + sigm(zi) * tanh_f(zg);
            h2buf[j] = sigm(zo) * tanh_f(c2);
        }
        __syncthreads();                                   // E: h2 ready

        if (j < CC) {
            float q = blin_s[j];
#pragma unroll
            for (int k4 = 0; k4 < HH / 4; ++k4) {
                float4 hv = ((const float4*)h2buf)[k4];
                float4 wv = ((const float4*)wlin_s)[j * (HH / 4) + k4];
                q = fmaf(wv.x, hv.x, q);
                q = fmaf(wv.y, hv.y, q);
                q = fmaf(wv.z, hv.z, q);
                q = fmaf(wv.w, hv.w, q);
            }
            qbuf[j] = q;
        }
        __syncthreads();                                   // F: q ready

        if (j < CC) {
            float4 g = *((const float4*)(gumbel + ((size_t)t * BB + b) * CC));
            float l0 = (qbuf[0] + g.x) * inv_tau;
            float l1 = (qbuf[1] + g.y) * inv_tau;
            float l2 = (qbuf[2] + g.z) * inv_tau;
            float l3 = (qbuf[3] + g.w) * inv_tau;
            float m = fmaxf(fmaxf(l0, l1), fmaxf(l2, l3));
            float e0 = __expf(l0 - m), e1 = __expf(l1 - m);
            float e2 = __expf(l2 - m), e3 = __expf(l3 - m);
            float inv = rcpf((e0 + e1) + (e2 + e3));
            float my = (j == 0) ? e0 : ((j == 1) ? e1 : ((j == 2) ? e2 : e3));
            float y = my * inv;
            xbuf[DD + j] = y;               // ct feedback (read after next barrier A)
            ob[t * CC + j] = y;
        }
        // next iteration's barrier A orders the ct write vs. layer-0 reads
    }
}

extern "C" void kernel_launch(void* const* d_in, const int* in_sizes, int n_in,
                              void* d_out, int out_size, void* d_ws, size_t ws_size,
                              hipStream_t stream) {
    const float* states = (const float*)d_in[0];
    const float* tau    = (const float*)d_in[1];
    const float* gumbel = (const float*)d_in[2];
    const float* w_ih0  = (const float*)d_in[3];
    const float* w_hh0  = (const float*)d_in[4];
    const float* b_ih0  = (const float*)d_in[5];
    const float* b_hh0  = (const float*)d_in[6];
    const float* w_ih1  = (const float*)d_in[7];
    const float* w_hh1  = (const float*)d_in[8];
    const float* b_ih1  = (const float*)d_in[9];
    const float* b_hh1  = (const float*)d_in[10];
    const float* w_lin  = (const float*)d_in[11];
    const float* b_lin  = (const float*)d_in[12];
    float* out = (float*)d_out;

    hipLaunchKernelGGL(lstm_opt_enc, dim3(BB), dim3(128), 0, stream,
                       states, tau, gumbel, w_ih0, w_hh0, b_ih0, b_hh0,
                       w_ih1, w_hh1, b_ih1, b_hh1, w_lin, b_lin, out);
}

// Round 3
// 1642.684 us; speedup vs baseline: 1.1803x; 1.1803x over previous
//
#include <hip/hip_runtime.h>

#define BB 512
#define TT 1024
#define DD 64
#define HH 32
#define CC 4

__device__ __forceinline__ float rcpf(float x) { return __builtin_amdgcn_rcpf(x); }
__device__ __forceinline__ float sigm(float x) { return rcpf(1.0f + __expf(-x)); }
__device__ __forceinline__ float tanh_f(float x) {
    return 1.0f - 2.0f * rcpf(__expf(2.0f * x) + 1.0f);
}

// Layout: block = 1 batch element, 128 threads = 2 waves.
// wave w owns hidden units [w*16, w*16+16); lane l = g*16 + u0 where
// g = gate type (0=i,1=f,2=g,3=o), u0 = unit-within-wave.
// i/f/g/o combine is intra-wave (shfl_xor 16/32); only h1,h2 broadcasts
// cross waves -> 2 barriers/step. ct (gumbel-softmax output) is computed
// redundantly on every lane and stays in registers.
extern "C" __global__ void __launch_bounds__(128, 2)
lstm_opt_enc(const float* __restrict__ states,   // [B,T,D]
             const float* __restrict__ taup,     // [1]
             const float* __restrict__ gumbel,   // [T,B,1,C]
             const float* __restrict__ w_ih0,    // [128,68]
             const float* __restrict__ w_hh0,    // [128,32]
             const float* __restrict__ b_ih0,
             const float* __restrict__ b_hh0,
             const float* __restrict__ w_ih1,    // [128,32]
             const float* __restrict__ w_hh1,    // [128,32]
             const float* __restrict__ b_ih1,
             const float* __restrict__ b_hh1,
             const float* __restrict__ w_lin,    // [4,32]
             const float* __restrict__ b_lin,    // [4]
             float* __restrict__ out)            // [B,T,4]
{
    const int b   = blockIdx.x;
    const int tid = threadIdx.x;
    const int l   = tid & 63;
    const int wv  = tid >> 6;
    const int u0  = l & 15;
    const int g   = l >> 4;          // gate type / q-channel
    const int u   = wv * 16 + u0;    // global hidden unit
    const int r   = g * 32 + u;      // gate row (torch order i,f,g,o)

    __shared__ __align__(16) float xb[2][DD];    // x_t double buffer
    __shared__ __align__(16) float h1b[2][HH];
    __shared__ __align__(16) float h2b[2][HH];

    // ---- weights for gate row r into registers ----
    float wi0r[68], wh0r[HH], wi1r[HH], wh1r[HH];
#pragma unroll
    for (int k = 0; k < 68; ++k) wi0r[k] = w_ih0[r * 68 + k];
#pragma unroll
    for (int k = 0; k < HH; ++k) wh0r[k] = w_hh0[r * HH + k];
#pragma unroll
    for (int k = 0; k < HH; ++k) wi1r[k] = w_ih1[r * HH + k];
#pragma unroll
    for (int k = 0; k < HH; ++k) wh1r[k] = w_hh1[r * HH + k];
    const float bias0 = b_ih0[r] + b_hh0[r];
    const float bias1 = b_ih1[r] + b_hh1[r];
    const float inv_tau = rcpf(taup[0]);
    const float wl0 = w_lin[g * HH + u0];        // q-phase weights
    const float wl1 = w_lin[g * HH + u0 + 16];
    const float blc = b_lin[g];

    float cst1 = 0.f, cst2 = 0.f;                // cell state of unit u (redundant x4)
    float y0 = 1.f, y1 = 0.f, y2 = 0.f, y3 = 0.f; // ct = one-hot(0), in regs on all lanes

    const float* __restrict__ sb = states + (size_t)b * TT * DD;
    float* __restrict__ ob = out + (size_t)b * TT * CC;

    // prologue: x_0 to LDS, prefetch x_1, zero h buffers
    float xr = 0.f;
    if (tid < DD) xr = sb[tid];
    if (tid < HH) { h1b[0][tid] = 0.f; h2b[0][tid] = 0.f; }
    if (tid < DD) { xb[0][tid] = xr; xr = sb[DD + tid]; }
    __syncthreads();

    for (int t = 0; t < TT; ++t) {
        const int p = t & 1, np = p ^ 1;
        // stage x_{t+1}; prefetch x_{t+2} (latency hidden by this whole step)
        if (tid < DD) { xb[np][tid] = xr; }
        const int tn = (t + 2 < TT) ? t + 2 : TT - 1;
        if (tid < DD) { xr = sb[tn * DD + tid]; }
        const float4 gt = *(const float4*)(gumbel + ((size_t)t * BB + b) * CC);

        // ---- layer 0: z[r] = wi0 . [x_t, ct] + wh0 . h1_{t-1} + bias0 ----
        float a0 = bias0, a1 = 0.f, a2 = 0.f, a3 = 0.f;
        const float4* xv = (const float4*)xb[p];
#pragma unroll
        for (int k = 0; k < 16; ++k) {
            float4 x4 = xv[k];
            a0 = fmaf(wi0r[4 * k + 0], x4.x, a0);
            a1 = fmaf(wi0r[4 * k + 1], x4.y, a1);
            a2 = fmaf(wi0r[4 * k + 2], x4.z, a2);
            a3 = fmaf(wi0r[4 * k + 3], x4.w, a3);
        }
        a0 = fmaf(wi0r[64], y0, a0);
        a1 = fmaf(wi0r[65], y1, a1);
        a2 = fmaf(wi0r[66], y2, a2);
        a3 = fmaf(wi0r[67], y3, a3);
        const float4* h1v = (const float4*)h1b[p];
#pragma unroll
        for (int k = 0; k < 8; ++k) {
            float4 h4 = h1v[k];
            a0 = fmaf(wh0r[4 * k + 0], h4.x, a0);
            a1 = fmaf(wh0r[4 * k + 1], h4.y, a1);
            a2 = fmaf(wh0r[4 * k + 2], h4.z, a2);
            a3 = fmaf(wh0r[4 * k + 3], h4.w, a3);
        }
        float z = (a0 + a1) + (a2 + a3);

        // gather i,f,g,o for unit u (intra-wave)
        float v1  = __shfl_xor(z, 16, 64);
        float lo  = (g & 1) ? v1 : z;
        float hi  = (g & 1) ? z  : v1;
        float lo2 = __shfl_xor(lo, 32, 64);
        float hi2 = __shfl_xor(hi, 32, 64);
        float zi = (g < 2) ? lo  : lo2;
        float zf = (g < 2) ? hi  : hi2;
        float zg = (g < 2) ? lo2 : lo;
        float zo = (g < 2) ? hi2 : hi;
        cst1 = sigm(zf) * cst1 + sigm(zi) * tanh_f(zg);
        float h1new = sigm(zo) * tanh_f(cst1);
        if (g == 0) h1b[np][u] = h1new;
        __syncthreads();                                  // barrier 1: h1_t visible

        // ---- layer 1: z[r] = wi1 . h1_t + wh1 . h2_{t-1} + bias1 ----
        a0 = bias1; a1 = 0.f; a2 = 0.f; a3 = 0.f;
        const float4* h1n = (const float4*)h1b[np];
        const float4* h2v = (const float4*)h2b[p];
#pragma unroll
        for (int k = 0; k < 8; ++k) {
            float4 h4 = h1n[k];
            float4 g4 = h2v[k];
            a0 = fmaf(wi1r[4 * k + 0], h4.x, a0);
            a1 = fmaf(wi1r[4 * k + 1], h4.y, a1);
            a2 = fmaf(wi1r[4 * k + 2], h4.z, a2);
            a3 = fmaf(wi1r[4 * k + 3], h4.w, a3);
            a0 = fmaf(wh1r[4 * k + 0], g4.x, a0);
            a1 = fmaf(wh1r[4 * k + 1], g4.y, a1);
            a2 = fmaf(wh1r[4 * k + 2], g4.z, a2);
            a3 = fmaf(wh1r[4 * k + 3], g4.w, a3);
        }
        z = (a0 + a1) + (a2 + a3);
        v1  = __shfl_xor(z, 16, 64);
        lo  = (g & 1) ? v1 : z;
        hi  = (g & 1) ? z  : v1;
        lo2 = __shfl_xor(lo, 32, 64);
        hi2 = __shfl_xor(hi, 32, 64);
        zi = (g < 2) ? lo  : lo2;
        zf = (g < 2) ? hi  : hi2;
        zg = (g < 2) ? lo2 : lo;
        zo = (g < 2) ? hi2 : hi;
        cst2 = sigm(zf) * cst2 + sigm(zi) * tanh_f(zg);
        float h2new = sigm(zo) * tanh_f(cst2);
        if (g == 0) h2b[np][u] = h2new;
        __syncthreads();                                  // barrier 2: h2_t visible

        // ---- q = w_lin . h2 + b_lin, then softmax((q+g)/tau), redundant per lane ----
        float part = wl0 * h2b[np][u0] + wl1 * h2b[np][u0 + 16];
        part += __shfl_xor(part, 1, 64);
        part += __shfl_xor(part, 2, 64);
        part += __shfl_xor(part, 4, 64);
        part += __shfl_xor(part, 8, 64);
        float qown = part + blc;                 // q_g on all lanes of group g
        float t1 = __shfl_xor(qown, 16, 64);
        float t2 = __shfl_xor(qown, 32, 64);
        float t3 = __shfl_xor(t1, 32, 64);
        // q_j = t_{j ^ g}
        float q0 = (g == 0) ? qown : (g == 1) ? t1 : (g == 2) ? t2 : t3;
        float q1 = (g == 0) ? t1 : (g == 1) ? qown : (g == 2) ? t3 : t2;
        float q2 = (g == 0) ? t2 : (g == 1) ? t3 : (g == 2) ? qown : t1;
        float q3 = (g == 0) ? t3 : (g == 1) ? t2 : (g == 2) ? t1 : qown;
        float l0 = (q0 + gt.x) * inv_tau;
        float l1_ = (q1 + gt.y) * inv_tau;
        float l2 = (q2 + gt.z) * inv_tau;
        float l3 = (q3 + gt.w) * inv_tau;
        float m = fmaxf(fmaxf(l0, l1_), fmaxf(l2, l3));
        float e0 = __expf(l0 - m), e1 = __expf(l1_ - m);
        float e2 = __expf(l2 - m), e3 = __expf(l3 - m);
        float inv = rcpf((e0 + e1) + (e2 + e3));
        y0 = e0 * inv; y1 = e1 * inv; y2 = e2 * inv; y3 = e3 * inv;

        if (tid == 0) *(float4*)(ob + (size_t)t * CC) = make_float4(y0, y1, y2, y3);
    }
}

extern "C" void kernel_launch(void* const* d_in, const int* in_sizes, int n_in,
                              void* d_out, int out_size, void* d_ws, size_t ws_size,
                              hipStream_t stream) {
    const float* states = (const float*)d_in[0];
    const float* tau    = (const float*)d_in[1];
    const float* gumbel = (const float*)d_in[2];
    const float* w_ih0  = (const float*)d_in[3];
    const float* w_hh0  = (const float*)d_in[4];
    const float* b_ih0  = (const float*)d_in[5];
    const float* b_hh0  = (const float*)d_in[6];
    const float* w_ih1  = (const float*)d_in[7];
    const float* w_hh1  = (const float*)d_in[8];
    const float* b_ih1  = (const float*)d_in[9];
    const float* b_hh1  = (const float*)d_in[10];
    const float* w_lin  = (const float*)d_in[11];
    const float* b_lin  = (const float*)d_in[12];
    float* out = (float*)d_out;

    hipLaunchKernelGGL(lstm_opt_enc, dim3(BB), dim3(128), 0, stream,
                       states, tau, gumbel, w_ih0, w_hh0, b_ih0, b_hh0,
                       w_ih1, w_hh1, b_ih1, b_hh1, w_lin, b_lin, out);
}